// Round 6
// baseline (256.623 us; speedup 1.0000x reference)
//
#include <hip/hip_runtime.h>

#define SEQ   8192
#define MAXP  2048
#define NEGI  (-1000000000.0f)

// out[i][j] = (0 <= i-j-1 <= MAXP-2) ? table[i-j-1] : NEG_INF
// 256 MiB fp32 output, 8 KiB table (L1-resident) -> pure store-BW-bound.
// Harness fills prove 6.55 TB/s write achievable -> kernel floor ~41 us.
//
// Row-per-block: band bounds are block-uniform (SGPR), 8x unrolled
// independent float4 stores per thread, no grid-stride loop.
__global__ __launch_bounds__(256) void rpe_rows(const float* __restrict__ table,
                                                float* __restrict__ out) {
    const int i   = blockIdx.x;                 // row 0..8191
    const int tid = threadIdx.x;                // 0..255
    float4* __restrict__ row4 = reinterpret_cast<float4*>(out) + i * (SEQ / 4);

    // Valid band: columns j in [i-2047, i-1]; value = table[i-j-1], idx in [0,2046].
    const int jlo = i - (MAXP - 1);             // may be negative
    const int jhi = i - 1;                      // -1 for row 0 (empty band)

    const float4 neg4 = make_float4(NEGI, NEGI, NEGI, NEGI);

    #pragma unroll
    for (int q = 0; q < 8; ++q) {
        const int f  = q * 256 + tid;           // float4 index within row, 0..2047
        const int j0 = f << 2;                  // first column of this float4
        float4 v;
        if (j0 + 3 < jlo || j0 > jhi) {
            // whole float4 outside band (wave-uniform almost everywhere)
            v = neg4;
        } else {
            const int d0 = i - j0 - 1;          // table idx for elem 0; elem k: d0-k
            v.x = ((unsigned)(d0    ) < (unsigned)(MAXP - 1)) ? table[d0    ] : NEGI;
            v.y = ((unsigned)(d0 - 1) < (unsigned)(MAXP - 1)) ? table[d0 - 1] : NEGI;
            v.z = ((unsigned)(d0 - 2) < (unsigned)(MAXP - 1)) ? table[d0 - 2] : NEGI;
            v.w = ((unsigned)(d0 - 3) < (unsigned)(MAXP - 1)) ? table[d0 - 3] : NEGI;
        }
        row4[f] = v;
    }
}

extern "C" void kernel_launch(void* const* d_in, const int* in_sizes, int n_in,
                              void* d_out, int out_size, void* d_ws, size_t ws_size,
                              hipStream_t stream) {
    const float* table = (const float*)d_in[0];
    float* out = (float*)d_out;
    // One block per row: 8192 blocks x 256 threads (32 blocks/CU queued).
    rpe_rows<<<SEQ, 256, 0, stream>>>(table, out);
}